// Round 7
// baseline (3782.383 us; speedup 1.0000x reference)
//
#include <hip/hip_runtime.h>
#include <cstdint>
#include <cstddef>

typedef unsigned short u16;
typedef unsigned int   u32;

#define B_    2
#define N_    1024
#define K_    48
#define H_    128
#define CAT_  384
#define FF_   512
#define EPS_  1e-5f
#define INV_SCALE (1.0f/48.0f)

__device__ __forceinline__ float bf2f(u16 u){ u32 x=((u32)u)<<16; float f; __builtin_memcpy(&f,&x,4); return f; }
__device__ __forceinline__ float gelu_ex(float x){ return 0.5f*x*(1.0f+erff(x*0.7071067811865475f)); }

__device__ __forceinline__ float ldf(const void* p, size_t i, int bf){
    return bf ? bf2f(((const u16*)p)[i]) : ((const float*)p)[i];
}
// 8 consecutive elems -> f32 LDS
__device__ __forceinline__ void cp8f(float* dst, const void* src, size_t eoff, int bf){
    if (bf) { const u16* s = (const u16*)src + eoff; for (int j=0;j<8;j++) dst[j]=bf2f(s[j]); }
    else {
        const float4* s = (const float4*)((const float*)src + eoff);
        *(float4*)dst = s[0]; *(float4*)(dst+4) = s[1];
    }
}

// 1 -> bf16, 0 -> fp32 (contract says fp32; probe is insurance)
__device__ int probe_f(const void* p, int n_elems){
    const u32 w0 = ((const u32*)p)[0];
    if (w0 == 0x3F803F80u) return 1;
    if (w0 == 0x3F800000u) return 0;
    const u16* s = (const u16*)p;
    int m = n_elems < 128 ? n_elems : 128;
    for (int j = 0; j < m; j++) {
        float v = fabsf(bf2f(s[j]));
        if (v > 1e6f) return 0;
    }
    return 1;
}
// 1 -> int64 storage, 0 -> int32 (contract says int32; insurance)
__device__ int probe_i(const int* p){
    const u32* s = (const u32*)p;
    for (int j = 0; j < 128; j++) if (s[2*j+1] != 0u) return 0;
    return 1;
}

// ================= node kernel: fp32 VALU =================
__global__ void __launch_bounds__(256)
node_valu(const void* __restrict__ hV, const void* __restrict__ hE, const int* __restrict__ Eidx,
          const void* __restrict__ maskV, const void* __restrict__ maskAtt,
          const void* __restrict__ W1, const void* __restrict__ b1,
          const void* __restrict__ W2, const void* __restrict__ b2,
          const void* __restrict__ W3, const void* __restrict__ b3,
          const void* __restrict__ Win, const void* __restrict__ bin,
          const void* __restrict__ Wout, const void* __restrict__ bout,
          const void* __restrict__ g1, const void* __restrict__ be1,
          const void* __restrict__ g2, const void* __restrict__ be2,
          float* __restrict__ outV)
{
    __shared__ float Xq[12*CAT_];          // quarter tile; layer3 output aliases it
    __shared__ float Yq[12*H_], Y2q[12*H_];
    __shared__ float macc[H_];
    __shared__ float hbuf[H_], hvn1[H_], hid[FF_];
    __shared__ float matt[K_];
    __shared__ int   idxs[K_];
    __shared__ float stats[2];
    __shared__ int   fl[20];

    const int bn  = blockIdx.x;
    const int b   = bn >> 10;
    const int tid = threadIdx.x;
    const int lane = tid & 63, w = tid >> 6;

    if (tid == 0)  fl[0]  = probe_f(hV,   1024);
    if (tid == 1)  fl[1]  = probe_f(hE,   1024);
    if (tid == 2)  fl[2]  = probe_i(Eidx);
    if (tid == 3)  fl[3]  = probe_f(maskV, B_*N_);
    if (tid == 4)  fl[4]  = probe_f(maskAtt, 1024);
    if (tid == 5)  fl[5]  = probe_f(W1,  1024);
    if (tid == 6)  fl[6]  = probe_f(b1,  H_);
    if (tid == 7)  fl[7]  = probe_f(W2,  1024);
    if (tid == 8)  fl[8]  = probe_f(b2,  H_);
    if (tid == 9)  fl[9]  = probe_f(W3,  1024);
    if (tid == 10) fl[10] = probe_f(b3,  H_);
    if (tid == 11) fl[11] = probe_f(Win, 1024);
    if (tid == 12) fl[12] = probe_f(bin, FF_);
    if (tid == 13) fl[13] = probe_f(Wout,1024);
    if (tid == 14) fl[14] = probe_f(bout,H_);
    if (tid == 15) fl[15] = probe_f(g1,  H_);
    if (tid == 16) fl[16] = probe_f(be1, H_);
    if (tid == 17) fl[17] = probe_f(g2,  H_);
    if (tid == 18) fl[18] = probe_f(be2, H_);
    __syncthreads();

    const int fHV = fl[0], fHE = fl[1], fID = fl[2], fMV = fl[3], fMA = fl[4];
    const int fW1 = fl[5], fb1 = fl[6], fW2 = fl[7], fb2 = fl[8], fW3 = fl[9], fb3 = fl[10];
    const int fWin = fl[11], fbin = fl[12], fWout = fl[13], fbout = fl[14];
    const int fg1 = fl[15], fbe1 = fl[16], fg2 = fl[17], fbe2 = fl[18];

    if (tid < K_) {
        const int base = bn*K_ + tid;
        idxs[tid] = fID ? Eidx[2*base] : Eidx[base];
        matt[tid] = ldf(maskAtt, base, fMA);
    }
    if (tid < H_) macc[tid] = 0.f;
    __syncthreads();

    for (int qt = 0; qt < 4; qt++) {
        for (int u = tid; u < 12*48; u += 256) {
            const int row = u / 48, c = u % 48;
            const int seg = c >> 4, c8 = (c & 15) << 3;
            const int gr  = qt*12 + row;
            size_t eoff; const void* src; int f;
            if (seg == 0)      { src = hV; eoff = (size_t)bn*H_ + c8; f = fHV; }
            else if (seg == 1) { src = hE; eoff = ((size_t)bn*K_ + gr)*H_ + c8; f = fHE; }
            else               { src = hV; eoff = ((size_t)b*N_ + idxs[gr])*H_ + c8; f = fHV; }
            cp8f(&Xq[row*CAT_ + seg*H_ + c8], src, eoff, f);
        }
        __syncthreads();
        for (int ii = 0; ii < 6; ii++) {
            const int idx = tid + 256*ii, r = idx >> 7, o = idx & 127;
            float a = 0.f;
            for (int k = 0; k < CAT_; k++) a += Xq[r*CAT_ + k] * ldf(W1, (size_t)k*H_ + o, fW1);
            Yq[r*H_ + o] = gelu_ex(a + ldf(b1, o, fb1));
        }
        __syncthreads();
        for (int ii = 0; ii < 6; ii++) {
            const int idx = tid + 256*ii, r = idx >> 7, o = idx & 127;
            float a = 0.f;
            for (int k = 0; k < H_; k++) a += Yq[r*H_ + k] * ldf(W2, (size_t)k*H_ + o, fW2);
            Y2q[r*H_ + o] = gelu_ex(a + ldf(b2, o, fb2));
        }
        __syncthreads();
        float* Mq = Xq;
        for (int ii = 0; ii < 6; ii++) {
            const int idx = tid + 256*ii, r = idx >> 7, o = idx & 127;
            float a = 0.f;
            for (int k = 0; k < H_; k++) a += Y2q[r*H_ + k] * ldf(W3, (size_t)k*H_ + o, fW3);
            Mq[r*H_ + o] = a + ldf(b3, o, fb3);
        }
        __syncthreads();
        if (tid < H_) {
            float s = 0.f;
            for (int r = 0; r < 12; r++) s += matt[qt*12 + r] * Mq[r*H_ + tid];
            macc[tid] += s;
        }
        __syncthreads();
    }

    // ---- LN1 ----
    if (tid < H_) hbuf[tid] = ldf(hV, (size_t)bn*H_ + tid, fHV) + macc[tid]*INV_SCALE;
    __syncthreads();
    if (w == 0) {
        float a = hbuf[lane], c = hbuf[lane+64];
        float s = a + c, ss = a*a + c*c;
        for (int off=32; off>0; off>>=1) { s += __shfl_xor(s,off); ss += __shfl_xor(ss,off); }
        if (lane == 0) { float m = s*(1.f/H_); stats[0]=m; stats[1]=rsqrtf(ss*(1.f/H_)-m*m+EPS_); }
    }
    __syncthreads();
    if (tid < H_) hvn1[tid] = (hbuf[tid]-stats[0])*stats[1]*ldf(g1,tid,fg1) + ldf(be1,tid,fbe1);
    __syncthreads();

    // ---- FFN ----
    for (int j = tid; j < FF_; j += 256) {
        float a = 0.f;
        for (int k = 0; k < H_; k++) a += hvn1[k] * ldf(Win, (size_t)k*FF_ + j, fWin);
        hid[j] = gelu_ex(a + ldf(bin, j, fbin));
    }
    __syncthreads();
    if (tid < H_) {
        float a = 0.f;
        for (int k = 0; k < FF_; k++) a += hid[k] * ldf(Wout, (size_t)k*H_ + tid, fWout);
        hbuf[tid] = hvn1[tid] + a + ldf(bout, tid, fbout);
    }
    __syncthreads();
    // ---- LN2 + mask ----
    if (w == 0) {
        float a = hbuf[lane], c = hbuf[lane+64];
        float s = a + c, ss = a*a + c*c;
        for (int off=32; off>0; off>>=1) { s += __shfl_xor(s,off); ss += __shfl_xor(ss,off); }
        if (lane == 0) { float m = s*(1.f/H_); stats[0]=m; stats[1]=rsqrtf(ss*(1.f/H_)-m*m+EPS_); }
    }
    __syncthreads();
    if (tid < H_) {
        float v = (hbuf[tid]-stats[0])*stats[1]*ldf(g2,tid,fg2) + ldf(be2,tid,fbe2);
        v *= ldf(maskV, bn, fMV);
        outV[(size_t)bn*H_ + tid] = v;          // *** fp32 store (output dtype = float32) ***
    }
}

// ================= edge kernel: fp32 VALU =================
// gathers updated h_Vn (fp32) from outV written by node_valu in prior dispatch
__global__ void __launch_bounds__(256)
edge_valu(const float* __restrict__ outV, const void* __restrict__ hE, const int* __restrict__ Eidx,
          const void* __restrict__ W11, const void* __restrict__ b11,
          const void* __restrict__ W12, const void* __restrict__ b12,
          const void* __restrict__ W13, const void* __restrict__ b13,
          const void* __restrict__ g3, const void* __restrict__ be3,
          float* __restrict__ outE)
{
    __shared__ float Xq[12*CAT_];
    __shared__ float Yq[12*H_], Y2q[12*H_];
    __shared__ int   idxs[K_];
    __shared__ int   fl[12];

    const int bn  = blockIdx.x;
    const int b   = bn >> 10;
    const int tid = threadIdx.x;
    const int lane = tid & 63, w = tid >> 6;

    if (tid == 0) fl[0] = probe_f(hE, 1024);
    if (tid == 1) fl[1] = probe_i(Eidx);
    if (tid == 2) fl[2] = probe_f(W11, 1024);
    if (tid == 3) fl[3] = probe_f(b11, H_);
    if (tid == 4) fl[4] = probe_f(W12, 1024);
    if (tid == 5) fl[5] = probe_f(b12, H_);
    if (tid == 6) fl[6] = probe_f(W13, 1024);
    if (tid == 7) fl[7] = probe_f(b13, H_);
    if (tid == 8) fl[8] = probe_f(g3, H_);
    if (tid == 9) fl[9] = probe_f(be3, H_);
    __syncthreads();

    const int fHE = fl[0], fID = fl[1];
    const int fW11 = fl[2], fb11 = fl[3], fW12 = fl[4], fb12 = fl[5], fW13 = fl[6], fb13 = fl[7];
    const int fg3 = fl[8], fbe3 = fl[9];

    if (tid < K_) {
        const int base = bn*K_ + tid;
        idxs[tid] = fID ? Eidx[2*base] : Eidx[base];
    }
    __syncthreads();

    for (int qt = 0; qt < 4; qt++) {
        for (int u = tid; u < 12*48; u += 256) {
            const int row = u / 48, c = u % 48;
            const int seg = c >> 4, c8 = (c & 15) << 3;
            const int gr  = qt*12 + row;
            float* dst = &Xq[row*CAT_ + seg*H_ + c8];
            if (seg == 1) {
                cp8f(dst, hE, ((size_t)bn*K_ + gr)*H_ + c8, fHE);
            } else {
                const size_t eoff = (seg == 0) ? ((size_t)bn*H_ + c8)
                                               : (((size_t)b*N_ + idxs[gr])*H_ + c8);
                cp8f(dst, outV, eoff, 0);       // fp32
            }
        }
        __syncthreads();
        for (int ii = 0; ii < 6; ii++) {
            const int idx = tid + 256*ii, r = idx >> 7, o = idx & 127;
            float a = 0.f;
            for (int k = 0; k < CAT_; k++) a += Xq[r*CAT_ + k] * ldf(W11, (size_t)k*H_ + o, fW11);
            Yq[r*H_ + o] = gelu_ex(a + ldf(b11, o, fb11));
        }
        __syncthreads();
        for (int ii = 0; ii < 6; ii++) {
            const int idx = tid + 256*ii, r = idx >> 7, o = idx & 127;
            float a = 0.f;
            for (int k = 0; k < H_; k++) a += Yq[r*H_ + k] * ldf(W12, (size_t)k*H_ + o, fW12);
            Y2q[r*H_ + o] = gelu_ex(a + ldf(b12, o, fb12));
        }
        __syncthreads();
        float* Mq = Xq;   // alias: [12][128] fp32 message tile
        for (int ii = 0; ii < 6; ii++) {
            const int idx = tid + 256*ii, r = idx >> 7, o = idx & 127;
            float a = 0.f;
            for (int k = 0; k < H_; k++) a += Y2q[r*H_ + k] * ldf(W13, (size_t)k*H_ + o, fW13);
            Mq[r*H_ + o] = a + ldf(b13, o, fb13);
        }
        __syncthreads();

        // LN3 + fp32 store for these 12 rows: one wave per row
        for (int row = w; row < 12; row += 4) {
            const int gr = qt*12 + row;
            const size_t e0 = ((size_t)bn*K_ + gr)*H_;
            float v0 = ldf(hE, e0 + lane,      fHE) + Mq[row*H_ + lane];
            float v1 = ldf(hE, e0 + lane + 64, fHE) + Mq[row*H_ + lane + 64];
            float s = v0+v1, ss = v0*v0+v1*v1;
            for (int off=32; off>0; off>>=1) { s += __shfl_xor(s,off); ss += __shfl_xor(ss,off); }
            const float m = s*(1.f/H_);
            const float rstd = rsqrtf(ss*(1.f/H_) - m*m + EPS_);
            outE[e0 + lane]      = (v0-m)*rstd*ldf(g3,lane,fg3)    + ldf(be3,lane,fbe3);
            outE[e0 + lane + 64] = (v1-m)*rstd*ldf(g3,lane+64,fg3) + ldf(be3,lane+64,fbe3);
        }
        __syncthreads();   // Mq (Xq) reused by next qt staging
    }
}

extern "C" void kernel_launch(void* const* d_in, const int* in_sizes, int n_in,
                              void* d_out, int out_size, void* d_ws, size_t ws_size,
                              hipStream_t stream)
{
    const void* hV      = d_in[0];
    const void* hE      = d_in[1];
    const int*  Eidx    = (const int*)d_in[2];
    const void* maskV   = d_in[3];
    const void* maskAtt = d_in[4];
    const void* W1w  = d_in[5];  const void* W1b  = d_in[6];
    const void* W2w  = d_in[7];  const void* W2b  = d_in[8];
    const void* W3w  = d_in[9];  const void* W3b  = d_in[10];
    const void* W11w = d_in[11]; const void* W11b = d_in[12];
    const void* W12w = d_in[13]; const void* W12b = d_in[14];
    const void* W13w = d_in[15]; const void* W13b = d_in[16];
    const void* Winw = d_in[17]; const void* Winb = d_in[18];
    const void* Woutw= d_in[19]; const void* Woutb= d_in[20];
    const void* ln1g = d_in[21]; const void* ln1b = d_in[22];
    const void* ln2g = d_in[23]; const void* ln2b = d_in[24];
    const void* ln3g = d_in[25]; const void* ln3b = d_in[26];

    float* outV = (float*)d_out;                  // output dtype = reference output dtype = fp32
    float* outE = outV + (size_t)B_*N_*H_;

    (void)d_ws; (void)ws_size; (void)n_in;

    hipLaunchKernelGGL(node_valu, dim3(B_*N_), dim3(256), 0, stream,
                       hV, hE, Eidx, maskV, maskAtt,
                       W1w, W1b, W2w, W2b, W3w, W3b,
                       Winw, Winb, Woutw, Woutb,
                       ln1g, ln1b, ln2g, ln2b,
                       outV);
    hipLaunchKernelGGL(edge_valu, dim3(B_*N_), dim3(256), 0, stream,
                       outV, hE, Eidx,
                       W11w, W11b, W12w, W12b, W13w, W13b,
                       ln3g, ln3b, outE);
}

// Round 8
// 411.463 us; speedup vs baseline: 9.1925x; 9.1925x over previous
//
#include <hip/hip_runtime.h>
#include <cstdint>
#include <cstddef>

typedef unsigned short u16;
typedef unsigned int   u32;
typedef __bf16  bf16x8 __attribute__((ext_vector_type(8)));
typedef float   f32x4  __attribute__((ext_vector_type(4)));

#define B_    2
#define N_    1024
#define K_    48
#define H_    128
#define CAT_  384
#define FF_   512
#define XPAD  392   // bf16 row pitch for X tile (384+8), 16B-aligned rows
#define YPAD  136   // bf16 row pitch for Y tiles (128+8)
#define MPAD  132   // fp32 row pitch for edge M tile
#define EPS_  1e-5f
#define INV_SCALE (1.0f/48.0f)

__device__ __forceinline__ float bf2f(u16 u){ u32 x=((u32)u)<<16; float f; __builtin_memcpy(&f,&x,4); return f; }
__device__ __forceinline__ u16 f2bf(float f){ u32 x; __builtin_memcpy(&x,&f,4); x=(x+0x7FFFu+((x>>16)&1u))>>16; return (u16)x; }
__device__ __forceinline__ u32 pk2(float lo, float hi){ return (u32)f2bf(lo) | ((u32)f2bf(hi)<<16); }
__device__ __forceinline__ float gelu_ex(float x){ return 0.5f*x*(1.0f+erff(x*0.7071067811865475f)); }
__device__ __forceinline__ f32x4 fzero(){ f32x4 v; v[0]=0.f; v[1]=0.f; v[2]=0.f; v[3]=0.f; return v; }

__device__ __forceinline__ float ldf(const void* p, size_t i, int bf){
    return bf ? bf2f(((const u16*)p)[i]) : ((const float*)p)[i];
}
// 8 consecutive elems -> bf16 LDS (dtype-aware; contract says fp32, probe is insurance)
__device__ __forceinline__ void cp8(u16* dst, const void* src, size_t eoff, int bf){
    if (bf) { *(uint4*)dst = *(const uint4*)((const u16*)src + eoff); }
    else {
        const float4* s = (const float4*)((const float*)src + eoff);
        float4 a = s[0], b = s[1];
        uint4 o; o.x = pk2(a.x,a.y); o.y = pk2(a.z,a.w); o.z = pk2(b.x,b.y); o.w = pk2(b.z,b.w);
        *(uint4*)dst = o;
    }
}

// ---------------- dtype probes ----------------
__device__ int probe_f_d(const void* p, int n_elems){
    const u32 w0 = ((const u32*)p)[0];
    if (w0 == 0x3F803F80u) return 1;
    if (w0 == 0x3F800000u) return 0;
    const u16* s = (const u16*)p;
    int m = n_elems < 128 ? n_elems : 128;
    for (int j = 0; j < m; j++) { float v = fabsf(bf2f(s[j])); if (v > 1e6f) return 0; }
    return 1;
}
__device__ int probe_i_d(const int* p){
    const u32* s = (const u32*)p;
    for (int j = 0; j < 128; j++) if (s[2*j+1] != 0u) return 0;
    return 1;
}
struct Ptrs27 { const void* p[27]; int n[27]; };
__global__ void __launch_bounds__(64)
probe_dtypes(Ptrs27 ptrs, int* __restrict__ flags)
{
    const int t = blockIdx.x;
    if (threadIdx.x != 0) return;
    flags[t] = (t == 2) ? probe_i_d((const int*)ptrs.p[t]) : probe_f_d(ptrs.p[t], ptrs.n[t]);
}

// weight [ri][co] -> bf16 [co][ri]
__global__ void __launch_bounds__(256)
repack_t(const void* __restrict__ src, u16* __restrict__ dst, int rows_in, int cols_out,
         const int* __restrict__ flags, int fidx)
{
    const int bf = flags[fidx];
    int i = blockIdx.x*256 + threadIdx.x;
    if (i < rows_in*cols_out) {
        int o = i % cols_out, r = i / cols_out;
        dst[o*rows_in + r] = bf ? ((const u16*)src)[i] : f2bf(((const float*)src)[i]);
    }
}

__global__ void __launch_bounds__(256)
prep_idx(const int* __restrict__ src, int* __restrict__ dst, int n, const int* __restrict__ flags)
{
    const int w64 = flags[2];
    int i = blockIdx.x*256 + threadIdx.x;
    if (i < n) dst[i] = w64 ? src[2*i] : src[i];
}

// 48xKD (LDS, u16 pitch AP) @ KDx128 (bf16 W^T [128][KD]) -> acc[3][2]; wave w owns cols w*32..+31
template<int KD, int AP>
__device__ __forceinline__ void mfma3x2(const u16* As, const u16* __restrict__ wt, int tid, f32x4 acc[3][2])
{
    const int lane = tid & 63;
    const int l15  = lane & 15, q = lane >> 4;
    const int n0   = (tid >> 6) * 32;
    for (int k0 = 0; k0 < KD; k0 += 32) {
        const int ko = k0 + q*8;
        bf16x8 a0 = *(const bf16x8*)&As[(l15     )*AP + ko];
        bf16x8 a1 = *(const bf16x8*)&As[(l15 + 16)*AP + ko];
        bf16x8 a2 = *(const bf16x8*)&As[(l15 + 32)*AP + ko];
        bf16x8 b0 = *(const bf16x8*)&wt[(size_t)(n0      + l15)*KD + ko];
        bf16x8 b1 = *(const bf16x8*)&wt[(size_t)(n0 + 16 + l15)*KD + ko];
        acc[0][0] = __builtin_amdgcn_mfma_f32_16x16x32_bf16(a0,b0,acc[0][0],0,0,0);
        acc[1][0] = __builtin_amdgcn_mfma_f32_16x16x32_bf16(a1,b0,acc[1][0],0,0,0);
        acc[2][0] = __builtin_amdgcn_mfma_f32_16x16x32_bf16(a2,b0,acc[2][0],0,0,0);
        acc[0][1] = __builtin_amdgcn_mfma_f32_16x16x32_bf16(a0,b1,acc[0][1],0,0,0);
        acc[1][1] = __builtin_amdgcn_mfma_f32_16x16x32_bf16(a1,b1,acc[1][1],0,0,0);
        acc[2][1] = __builtin_amdgcn_mfma_f32_16x16x32_bf16(a2,b1,acc[2][1],0,0,0);
    }
}
// D[row=mt*16+(lane>>4)*4+r][col=(wave*32)+ct*16+(lane&15)]  (m89-verified C/D mapping)
__device__ __forceinline__ void epi_gelu(const f32x4 acc[3][2], const void* __restrict__ bias, int bf,
                                         u16* Outs, int tid)
{
    const int lane = tid & 63, l15 = lane & 15, q = lane >> 4, n0 = (tid>>6)*32;
    for (int ct = 0; ct < 2; ct++) {
        const int col = n0 + ct*16 + l15;
        const float bv = ldf(bias, col, bf);
        for (int mt = 0; mt < 3; mt++)
            for (int r = 0; r < 4; r++)
                Outs[(mt*16 + q*4 + r)*YPAD + col] = f2bf(gelu_ex(acc[mt][ct][r] + bv));
    }
}

// ================= node kernel: MFMA =================
__global__ void __launch_bounds__(256, 2)
node_mfma(const void* __restrict__ hV, const void* __restrict__ hE, const int* __restrict__ idxn,
          const void* __restrict__ maskV, const void* __restrict__ maskAtt,
          const u16* __restrict__ w1t, const void* __restrict__ b1,
          const u16* __restrict__ w2t, const void* __restrict__ b2,
          const u16* __restrict__ w3t, const void* __restrict__ b3,
          const u16* __restrict__ wintt, const void* __restrict__ bin,
          const u16* __restrict__ woutt, const void* __restrict__ bout,
          const void* __restrict__ g1, const void* __restrict__ be1,
          const void* __restrict__ g2, const void* __restrict__ be2,
          const int* __restrict__ flags,
          float* __restrict__ outV, u16* __restrict__ wsVn)
{
    __shared__ __align__(16) u16 Xs[K_*XPAD];     // X tile; later aliased as Y2 tile
    __shared__ __align__(16) u16 Y1s[K_*YPAD];    // Y1 tile; later aliased as fp32 hid[512]
    __shared__ float dhs[H_], hbuf[H_], hvn1[H_];
    __shared__ float matt[K_];
    __shared__ int   idxs[K_];
    __shared__ float stats[3];                    // mean, rstd, summask

    const int bn  = blockIdx.x;
    const int b   = bn >> 10;
    const int tid = threadIdx.x;
    const int lane = tid & 63, w = tid >> 6;

    const int fHV = flags[0], fHE = flags[1], fMV = flags[3], fMA = flags[4];
    const int fb1 = flags[6], fb2 = flags[8], fb3 = flags[10];
    const int fbin = flags[18], fbout = flags[20];
    const int fg1 = flags[21], fbe1 = flags[22], fg2 = flags[23], fbe2 = flags[24];

    if (tid < K_) { idxs[tid] = idxn[bn*K_ + tid]; matt[tid] = ldf(maskAtt, (size_t)bn*K_ + tid, fMA); }
    __syncthreads();
    if (tid == 0) { float s=0.f; for (int k=0;k<K_;k++) s += matt[k]; stats[2] = s; }

    for (int u = tid; u < 768; u += 256) {
        const int row = u >> 4, c8 = (u & 15) << 3;
        cp8(&Xs[row*XPAD + c8],        hV, (size_t)bn*H_ + c8, fHV);
        cp8(&Xs[row*XPAD + H_ + c8],   hE, ((size_t)bn*K_ + row)*H_ + c8, fHE);
        cp8(&Xs[row*XPAD + 2*H_ + c8], hV, ((size_t)b*N_ + idxs[row])*H_ + c8, fHV);
    }
    __syncthreads();

    f32x4 acc[3][2];
    for (int i=0;i<3;i++) for (int j=0;j<2;j++) acc[i][j]=fzero();
    mfma3x2<CAT_, XPAD>(Xs, w1t, tid, acc);
    epi_gelu(acc, b1, fb1, Y1s, tid);
    __syncthreads();                 // also: everyone done reading Xs

    u16* Y2s = Xs;                   // alias X region as Y2 tile (pitch YPAD)
    for (int i=0;i<3;i++) for (int j=0;j<2;j++) acc[i][j]=fzero();
    mfma3x2<H_, YPAD>(Y1s, w2t, tid, acc);
    epi_gelu(acc, b2, fb2, Y2s, tid);
    __syncthreads();

    for (int i=0;i<3;i++) for (int j=0;j<2;j++) acc[i][j]=fzero();
    mfma3x2<H_, YPAD>(Y2s, w3t, tid, acc);
    {   // masked sum over K rows -> dh (cols distributed across lanes/waves)
        const int l15 = lane & 15, q = lane >> 4, n0 = w*32;
        float s0=0.f, s1=0.f;
        for (int mt=0; mt<3; mt++)
            for (int r=0; r<4; r++) {
                const float mk = matt[mt*16 + q*4 + r];
                s0 += acc[mt][0][r]*mk;
                s1 += acc[mt][1][r]*mk;
            }
        s0 += __shfl_xor(s0,16); s0 += __shfl_xor(s0,32);
        s1 += __shfl_xor(s1,16); s1 += __shfl_xor(s1,32);
        if (q == 0) {
            const float sm = stats[2];
            dhs[n0+l15]    = (s0 + ldf(b3, n0+l15,    fb3)*sm) * INV_SCALE;
            dhs[n0+16+l15] = (s1 + ldf(b3, n0+16+l15, fb3)*sm) * INV_SCALE;
        }
    }
    __syncthreads();

    // ---- LN1 ----
    if (tid < H_) hbuf[tid] = ldf(hV, (size_t)bn*H_ + tid, fHV) + dhs[tid];
    __syncthreads();
    if (w == 0) {
        float a = hbuf[lane], c = hbuf[lane+64];
        float s = a + c, ss = a*a + c*c;
        for (int off=32; off>0; off>>=1) { s += __shfl_xor(s,off); ss += __shfl_xor(ss,off); }
        if (lane == 0) { float m = s*(1.f/H_); stats[0]=m; stats[1]=rsqrtf(ss*(1.f/H_)-m*m+EPS_); }
    }
    __syncthreads();
    if (tid < H_) hvn1[tid] = (hbuf[tid]-stats[0])*stats[1]*ldf(g1,tid,fg1) + ldf(be1,tid,fbe1);
    __syncthreads();

    // ---- FFN (bf16 weight rows, uint4 loads) ----
    float* hid = (float*)Y1s;        // alias Y1 region (dead) as fp32 hid[512]
    for (int j = tid; j < FF_; j += 256) {
        const uint4* wr = (const uint4*)(wintt + (size_t)j*H_);
        float a = 0.f;
        for (int i = 0; i < H_/8; i++) {
            uint4 u = wr[i];
            a += hvn1[8*i+0]*bf2f((u16)u.x) + hvn1[8*i+1]*bf2f((u16)(u.x>>16));
            a += hvn1[8*i+2]*bf2f((u16)u.y) + hvn1[8*i+3]*bf2f((u16)(u.y>>16));
            a += hvn1[8*i+4]*bf2f((u16)u.z) + hvn1[8*i+5]*bf2f((u16)(u.z>>16));
            a += hvn1[8*i+6]*bf2f((u16)u.w) + hvn1[8*i+7]*bf2f((u16)(u.w>>16));
        }
        hid[j] = gelu_ex(a + ldf(bin, j, fbin));
    }
    __syncthreads();
    if (tid < H_) {
        const uint4* wr = (const uint4*)(woutt + (size_t)tid*FF_);
        float a = 0.f;
        for (int i = 0; i < FF_/8; i++) {
            uint4 u = wr[i];
            a += hid[8*i+0]*bf2f((u16)u.x) + hid[8*i+1]*bf2f((u16)(u.x>>16));
            a += hid[8*i+2]*bf2f((u16)u.y) + hid[8*i+3]*bf2f((u16)(u.y>>16));
            a += hid[8*i+4]*bf2f((u16)u.z) + hid[8*i+5]*bf2f((u16)(u.z>>16));
            a += hid[8*i+6]*bf2f((u16)u.w) + hid[8*i+7]*bf2f((u16)(u.w>>16));
        }
        hbuf[tid] = hvn1[tid] + a + ldf(bout, tid, fbout);
    }
    __syncthreads();
    // ---- LN2 + mask ----
    if (w == 0) {
        float a = hbuf[lane], c = hbuf[lane+64];
        float s = a + c, ss = a*a + c*c;
        for (int off=32; off>0; off>>=1) { s += __shfl_xor(s,off); ss += __shfl_xor(ss,off); }
        if (lane == 0) { float m = s*(1.f/H_); stats[0]=m; stats[1]=rsqrtf(ss*(1.f/H_)-m*m+EPS_); }
    }
    __syncthreads();
    if (tid < H_) {
        float v = (hbuf[tid]-stats[0])*stats[1]*ldf(g2,tid,fg2) + ldf(be2,tid,fbe2);
        v *= ldf(maskV, bn, fMV);
        outV[(size_t)bn*H_ + tid] = v;          // fp32 output
        wsVn[(size_t)bn*H_ + tid] = f2bf(v);    // bf16 copy for edge staging
    }
}

// ================= edge kernel: MFMA =================
__global__ void __launch_bounds__(256, 2)
edge_mfma(const u16* __restrict__ wsVn, const void* __restrict__ hE, const int* __restrict__ idxn,
          const u16* __restrict__ w11t, const void* __restrict__ b11,
          const u16* __restrict__ w12t, const void* __restrict__ b12,
          const u16* __restrict__ w13t, const void* __restrict__ b13,
          const void* __restrict__ g3, const void* __restrict__ be3,
          const int* __restrict__ flags,
          float* __restrict__ outE)
{
    __shared__ __align__(16) u16 Xs[K_*XPAD];   // X tile; aliased as Y2, then fp32 M
    __shared__ __align__(16) u16 Y1s[K_*YPAD];
    __shared__ int idxs[K_];

    const int bn  = blockIdx.x;
    const int b   = bn >> 10;
    const int tid = threadIdx.x;
    const int lane = tid & 63, w = tid >> 6;

    const int fHE = flags[1];
    const int fb11 = flags[12], fb12 = flags[14], fb13 = flags[16];
    const int fg3 = flags[25], fbe3 = flags[26];

    if (tid < K_) idxs[tid] = idxn[bn*K_ + tid];
    __syncthreads();

    const u16* hVb = wsVn + (size_t)b*N_*H_;
    for (int u = tid; u < 768; u += 256) {
        const int row = u >> 4, c8 = (u & 15) << 3;
        *(uint4*)&Xs[row*XPAD + c8]        = *(const uint4*)&wsVn[(size_t)bn*H_ + c8];
        cp8(&Xs[row*XPAD + H_ + c8], hE, ((size_t)bn*K_ + row)*H_ + c8, fHE);
        *(uint4*)&Xs[row*XPAD + 2*H_ + c8] = *(const uint4*)&hVb[(size_t)idxs[row]*H_ + c8];
    }
    __syncthreads();

    f32x4 acc[3][2];
    for (int i=0;i<3;i++) for (int j=0;j<2;j++) acc[i][j]=fzero();
    mfma3x2<CAT_, XPAD>(Xs, w11t, tid, acc);
    epi_gelu(acc, b11, fb11, Y1s, tid);
    __syncthreads();

    u16* Y2s = Xs;
    for (int i=0;i<3;i++) for (int j=0;j<2;j++) acc[i][j]=fzero();
    mfma3x2<H_, YPAD>(Y1s, w12t, tid, acc);
    epi_gelu(acc, b12, fb12, Y2s, tid);
    __syncthreads();

    for (int i=0;i<3;i++) for (int j=0;j<2;j++) acc[i][j]=fzero();
    mfma3x2<H_, YPAD>(Y2s, w13t, tid, acc);
    __syncthreads();                  // all layer-3 reads of Y2 (Xs) done
    float* Ms = (float*)Xs;           // fp32 M tile [48][MPAD]
    {
        const int l15 = lane & 15, q = lane >> 4, n0 = w*32;
        for (int ct=0; ct<2; ct++) {
            const int col = n0 + ct*16 + l15;
            const float bv = ldf(b13, col, fb13);
            for (int mt=0; mt<3; mt++)
                for (int r=0; r<4; r++)
                    Ms[(mt*16 + q*4 + r)*MPAD + col] = acc[mt][ct][r] + bv;
        }
    }
    __syncthreads();

    // h_En = LN(h_E + M), one wave per row, fp32 store
    for (int row = w; row < K_; row += 4) {
        const size_t e0 = ((size_t)bn*K_ + row)*H_;
        float v0 = ldf(hE, e0 + lane,      fHE) + Ms[row*MPAD + lane];
        float v1 = ldf(hE, e0 + lane + 64, fHE) + Ms[row*MPAD + lane + 64];
        float s = v0+v1, ss = v0*v0+v1*v1;
        for (int off=32; off>0; off>>=1) { s += __shfl_xor(s,off); ss += __shfl_xor(ss,off); }
        const float m = s*(1.f/H_);
        const float rstd = rsqrtf(ss*(1.f/H_) - m*m + EPS_);
        outE[e0 + lane]      = (v0-m)*rstd*ldf(g3,lane,fg3)    + ldf(be3,lane,fbe3);
        outE[e0 + lane + 64] = (v1-m)*rstd*ldf(g3,lane+64,fg3) + ldf(be3,lane+64,fbe3);
    }
}

extern "C" void kernel_launch(void* const* d_in, const int* in_sizes, int n_in,
                              void* d_out, int out_size, void* d_ws, size_t ws_size,
                              hipStream_t stream)
{
    const void* hV      = d_in[0];
    const void* hE      = d_in[1];
    const int*  Eidx    = (const int*)d_in[2];
    const void* maskV   = d_in[3];
    const void* maskAtt = d_in[4];
    const void* W1w  = d_in[5];  const void* W1b  = d_in[6];
    const void* W2w  = d_in[7];  const void* W2b  = d_in[8];
    const void* W3w  = d_in[9];  const void* W3b  = d_in[10];
    const void* W11w = d_in[11]; const void* W11b = d_in[12];
    const void* W12w = d_in[13]; const void* W12b = d_in[14];
    const void* W13w = d_in[15]; const void* W13b = d_in[16];
    const void* Winw = d_in[17]; const void* Winb = d_in[18];
    const void* Woutw= d_in[19]; const void* Woutb= d_in[20];
    const void* ln1g = d_in[21]; const void* ln1b = d_in[22];
    const void* ln2g = d_in[23]; const void* ln2b = d_in[24];
    const void* ln3g = d_in[25]; const void* ln3b = d_in[26];

    // ws layout (u16 units)
    u16* ws    = (u16*)d_ws;
    u16* w1t   = ws;                        // 128*384
    u16* w2t   = w1t   + 128*384;           // 128*128
    u16* w3t   = w2t   + 128*128;
    u16* w11t  = w3t   + 128*128;           // 128*384
    u16* w12t  = w11t  + 128*384;
    u16* w13t  = w12t  + 128*128;
    u16* wintt = w13t  + 128*128;           // 512*128
    u16* woutt = wintt + 512*128;           // 128*512
    int* idxn  = (int*)(woutt + 128*512);   // 98304 int32
    u16* wsVn  = (u16*)(idxn + B_*N_*K_);   // 262144 bf16
    int* flags = (int*)(wsVn + B_*N_*H_);   // 27 ints

    Ptrs27 P;
    for (int i = 0; i < 27; i++) { P.p[i] = d_in[i]; P.n[i] = in_sizes[i]; }
    hipLaunchKernelGGL(probe_dtypes, dim3(27), dim3(64), 0, stream, P, flags);

    auto T = [&](const void* src, u16* dst, int ri, int co, int fidx) {
        hipLaunchKernelGGL(repack_t, dim3((ri*co+255)/256), dim3(256), 0, stream, src, dst, ri, co, flags, fidx);
    };
    T(W1w,  w1t,  384, 128, 5);
    T(W2w,  w2t,  128, 128, 7);
    T(W3w,  w3t,  128, 128, 9);
    T(W11w, w11t, 384, 128, 11);
    T(W12w, w12t, 128, 128, 13);
    T(W13w, w13t, 128, 128, 15);
    T(Winw, wintt, 128, 512, 17);
    T(Woutw,woutt, 512, 128, 19);
    hipLaunchKernelGGL(prep_idx, dim3((B_*N_*K_+255)/256), dim3(256), 0, stream, Eidx, idxn, B_*N_*K_, flags);

    float* outV = (float*)d_out;
    float* outE = outV + (size_t)B_*N_*H_;

    hipLaunchKernelGGL(node_mfma, dim3(B_*N_), dim3(256), 0, stream,
                       hV, hE, idxn, maskV, maskAtt,
                       w1t, W1b, w2t, W2b, w3t, W3b,
                       wintt, Winb, woutt, Woutb,
                       ln1g, ln1b, ln2g, ln2b,
                       flags, outV, wsVn);
    hipLaunchKernelGGL(edge_mfma, dim3(B_*N_), dim3(256), 0, stream,
                       wsVn, hE, idxn,
                       w11t, W11b, w12t, W12b, w13t, W13b,
                       ln3g, ln3b, flags, outE);
}